// Round 1
// baseline (19994.557 us; speedup 1.0000x reference)
//
#include <hip/hip_runtime.h>
#include <hip/hip_bf16.h>
#include <math.h>

#define S_   1000
#define B_   4
#define D_   1024
#define H_   16
#define HD_  64
#define L_   4
#define FF_  4096
#define N_   (S_*B_)   /* 4000 token rows */

// ---------------- embedding lookup ----------------
__global__ void embed_kernel(const int* __restrict__ tokens,
                             const float* __restrict__ emb,
                             float* __restrict__ x) {
    int n = blockIdx.x;                 // 0..N_-1, n = s*B + b
    int tok = tokens[n];
    const float4* src = (const float4*)(emb + (size_t)tok * D_);
    float4* dst = (float4*)(x + (size_t)n * D_);
    dst[threadIdx.x] = src[threadIdx.x];   // 256 threads * float4 = 1024
}

// ---------------- layernorm (one row per block, 256 thr) ----------------
__global__ __launch_bounds__(256)
void ln_kernel(const float* __restrict__ in,
               const float* __restrict__ g,
               const float* __restrict__ b,
               float* __restrict__ out) {
    int n = blockIdx.x;
    int tid = threadIdx.x;
    const float4* row = (const float4*)(in + (size_t)n * D_);
    float4 v = row[tid];
    float s  = v.x + v.y + v.z + v.w;
    float sq = v.x*v.x + v.y*v.y + v.z*v.z + v.w*v.w;
    #pragma unroll
    for (int off = 32; off; off >>= 1) {
        s  += __shfl_down(s, off);
        sq += __shfl_down(sq, off);
    }
    __shared__ float rs[4], rq[4];
    int wid = tid >> 6;
    if ((tid & 63) == 0) { rs[wid] = s; rq[wid] = sq; }
    __syncthreads();
    s  = rs[0] + rs[1] + rs[2] + rs[3];
    sq = rq[0] + rq[1] + rq[2] + rq[3];
    float mean = s * (1.0f / D_);
    float var  = sq * (1.0f / D_) - mean * mean;
    float rstd = rsqrtf(var + 1e-5f);
    float4 gg = ((const float4*)g)[tid];
    float4 bb = ((const float4*)b)[tid];
    float4 o;
    o.x = (v.x - mean) * rstd * gg.x + bb.x;
    o.y = (v.y - mean) * rstd * gg.y + bb.y;
    o.z = (v.z - mean) * rstd * gg.z + bb.z;
    o.w = (v.w - mean) * rstd * gg.w + bb.w;
    ((float4*)(out + (size_t)n * D_))[tid] = o;
}

// ---------------- fp32 tiled GEMM: C[m,e] = (sum_d A[m,d]*W[e,d] + bias[e])*scale ----------------
// ACT: 0=none, 1=exact gelu.  RES: add residual res[m,e] after act.
template<int ACT, bool RES>
__global__ __launch_bounds__(256)
void gemm_kernel(const float* __restrict__ A,     // [M,K] row-major
                 const float* __restrict__ W,     // [E,K] row-major
                 const float* __restrict__ bias,  // [E]
                 const float* __restrict__ res,   // [M,E] or null
                 float* __restrict__ C,           // [M,E]
                 int M, int K, int E, float scale) {
    __shared__ float As[32][64];
    __shared__ float Ws[32][64];
    int tid = threadIdx.x;
    int m0 = blockIdx.x * 64, e0 = blockIdx.y * 64;
    int tx = tid & 15, ty = tid >> 4;
    int lrow = tid >> 2;          // 0..63
    int lkc  = (tid & 3) * 8;     // 0,8,16,24
    float acc[4][4] = {};
    const float* Arow = A + (size_t)(m0 + lrow) * K + lkc;
    const float* Wrow = W + (size_t)(e0 + lrow) * K + lkc;
    bool aval = (m0 + lrow) < M;

    for (int k0 = 0; k0 < K; k0 += 32) {
        float4 a0 = make_float4(0.f,0.f,0.f,0.f), a1 = a0;
        if (aval) {
            a0 = *(const float4*)(Arow + k0);
            a1 = *(const float4*)(Arow + k0 + 4);
        }
        float4 w0 = *(const float4*)(Wrow + k0);
        float4 w1 = *(const float4*)(Wrow + k0 + 4);
        As[lkc+0][lrow] = a0.x; As[lkc+1][lrow] = a0.y;
        As[lkc+2][lrow] = a0.z; As[lkc+3][lrow] = a0.w;
        As[lkc+4][lrow] = a1.x; As[lkc+5][lrow] = a1.y;
        As[lkc+6][lrow] = a1.z; As[lkc+7][lrow] = a1.w;
        Ws[lkc+0][lrow] = w0.x; Ws[lkc+1][lrow] = w0.y;
        Ws[lkc+2][lrow] = w0.z; Ws[lkc+3][lrow] = w0.w;
        Ws[lkc+4][lrow] = w1.x; Ws[lkc+5][lrow] = w1.y;
        Ws[lkc+6][lrow] = w1.z; Ws[lkc+7][lrow] = w1.w;
        __syncthreads();
        #pragma unroll
        for (int kk = 0; kk < 32; ++kk) {
            float4 a = *(const float4*)(&As[kk][ty*4]);
            float4 w = *(const float4*)(&Ws[kk][tx*4]);
            acc[0][0] += a.x*w.x; acc[0][1] += a.x*w.y; acc[0][2] += a.x*w.z; acc[0][3] += a.x*w.w;
            acc[1][0] += a.y*w.x; acc[1][1] += a.y*w.y; acc[1][2] += a.y*w.z; acc[1][3] += a.y*w.w;
            acc[2][0] += a.z*w.x; acc[2][1] += a.z*w.y; acc[2][2] += a.z*w.z; acc[2][3] += a.z*w.w;
            acc[3][0] += a.w*w.x; acc[3][1] += a.w*w.y; acc[3][2] += a.w*w.z; acc[3][3] += a.w*w.w;
        }
        __syncthreads();
    }
    #pragma unroll
    for (int i = 0; i < 4; ++i) {
        int m = m0 + ty*4 + i;
        if (m >= M) continue;
        #pragma unroll
        for (int j = 0; j < 4; ++j) {
            int e = e0 + tx*4 + j;
            float val = (acc[i][j] + bias[e]) * scale;
            if (ACT == 1) val = 0.5f * val * (1.0f + erff(val * 0.70710678118654752f));
            if (RES) val += res[(size_t)m * E + e];
            C[(size_t)m * E + e] = val;
        }
    }
}

// ---------------- RoPE (in place on q or k, [N, H*HD] layout) ----------------
__global__ void rope_kernel(float* __restrict__ x) {
    int idx = blockIdx.x * 256 + threadIdx.x;   // N_*H_*32 pairs
    if (idx >= N_ * H_ * 32) return;
    int j = idx & 31;
    int h = (idx >> 5) & (H_ - 1);
    int n = idx >> 9;
    int s = n >> 2;                 // n = s*B + b, B=4
    // inv_freq[j] = 10000^(-j/32)
    float inv = expf(-(float)j * 0.2878231366242557f);  // ln(10000)/32
    float ang = (float)s * inv;
    float sn, cs;
    sincosf(ang, &sn, &cs);
    float* p = x + (size_t)n * D_ + h * HD_ + j;
    float a = p[0], b = p[32];
    p[0]  = a * cs - b * sn;
    p[32] = b * cs + a * sn;
}

// ---------------- attention: one (b,h,s) row per block ----------------
__global__ __launch_bounds__(256)
void attn_kernel(const float* __restrict__ q, const float* __restrict__ k,
                 const float* __restrict__ v, float* __restrict__ o) {
    int bid = blockIdx.x;
    int s  = bid % S_;
    int bh = bid / S_;
    int b  = bh >> 4;       // bh / H_
    int h  = bh & (H_ - 1);
    int tid = threadIdx.x;
    int n = s * B_ + b;

    __shared__ float qs[HD_];
    __shared__ float ss[1024];
    __shared__ float red1[4], red2[4];
    __shared__ float part[4][HD_];

    if (tid < HD_) qs[tid] = q[(size_t)n * D_ + h * HD_ + tid];
    __syncthreads();

    float lmax = -1e30f;
    for (int t = tid; t < S_; t += 256) {
        const float* kr = k + ((size_t)t * B_ + b) * D_ + h * HD_;
        float sc = 0.f;
        #pragma unroll
        for (int jj = 0; jj < 16; ++jj) {
            float4 kv = *(const float4*)(kr + jj*4);
            float4 qv = *(const float4*)(&qs[jj*4]);
            sc += qv.x*kv.x + qv.y*kv.y + qv.z*kv.z + qv.w*kv.w;
        }
        ss[t] = sc;
        lmax = fmaxf(lmax, sc);
    }
    #pragma unroll
    for (int off = 32; off; off >>= 1) lmax = fmaxf(lmax, __shfl_down(lmax, off));
    int wid = tid >> 6;
    if ((tid & 63) == 0) red1[wid] = lmax;
    __syncthreads();
    float mx = fmaxf(fmaxf(red1[0], red1[1]), fmaxf(red1[2], red1[3]));

    float lsum = 0.f;
    for (int t = tid; t < S_; t += 256) {
        float e = __expf(ss[t] - mx);
        ss[t] = e;
        lsum += e;
    }
    #pragma unroll
    for (int off = 32; off; off >>= 1) lsum += __shfl_down(lsum, off);
    if ((tid & 63) == 0) red2[wid] = lsum;
    __syncthreads();   // also fences the ss[] exp writes before PV reads
    float inv = 1.0f / (red2[0] + red2[1] + red2[2] + red2[3]);

    int d = tid & 63, pt = tid >> 6;
    float acc = 0.f;
    for (int t = pt; t < S_; t += 4)
        acc += ss[t] * v[((size_t)t * B_ + b) * D_ + h * HD_ + d];
    part[pt][d] = acc;
    __syncthreads();
    if (tid < HD_) {
        float r = (part[0][tid] + part[1][tid] + part[2][tid] + part[3][tid]) * inv;
        o[(size_t)n * D_ + h * HD_ + tid] = r;
    }
}

extern "C" void kernel_launch(void* const* d_in, const int* in_sizes, int n_in,
                              void* d_out, int out_size, void* d_ws, size_t ws_size,
                              hipStream_t stream) {
    const int*   tokens = (const int*)  d_in[0];
    const float* Wemb   = (const float*)d_in[1];
    const float* Wq     = (const float*)d_in[2];
    const float* bq     = (const float*)d_in[3];
    const float* Wk     = (const float*)d_in[4];
    const float* bk     = (const float*)d_in[5];
    const float* Wv     = (const float*)d_in[6];
    const float* bv     = (const float*)d_in[7];
    const float* Wo     = (const float*)d_in[8];
    const float* bo     = (const float*)d_in[9];
    const float* ln1g   = (const float*)d_in[10];
    const float* ln1b   = (const float*)d_in[11];
    const float* ln2g   = (const float*)d_in[12];
    const float* ln2b   = (const float*)d_in[13];
    const float* W1     = (const float*)d_in[14];
    const float* b1     = (const float*)d_in[15];
    const float* W2     = (const float*)d_in[16];
    const float* b2     = (const float*)d_in[17];
    const float* Wout   = (const float*)d_in[18];
    const float* bout   = (const float*)d_in[19];
    float* out = (float*)d_out;

    float* ws = (float*)d_ws;
    const size_t ND = (size_t)N_ * D_;
    float* x    = ws;
    float* hbuf = x    + ND;
    float* q    = hbuf + ND;
    float* kk   = q    + ND;
    float* vv   = kk   + ND;
    float* ob   = vv   + ND;
    float* f1   = ob   + ND;        // N_*FF_

    dim3 blk(256);
    embed_kernel<<<N_, blk, 0, stream>>>(tokens, Wemb, x);

    const float qscale = 0.125f;    // HD^-0.5
    dim3 gQ((N_ + 63) / 64, D_ / 64);
    dim3 gF1((N_ + 63) / 64, FF_ / 64);
    dim3 gOut((N_ + 63) / 64, 1);
    int rth = N_ * H_ * 32;
    dim3 gR((rth + 255) / 256);

    for (int l = 0; l < L_; ++l) {
        ln_kernel<<<N_, blk, 0, stream>>>(x, ln1g + l*D_, ln1b + l*D_, hbuf);
        gemm_kernel<0,false><<<gQ, blk, 0, stream>>>(hbuf, Wq + (size_t)l*D_*D_, bq + l*D_, nullptr, q,  N_, D_, D_, qscale);
        gemm_kernel<0,false><<<gQ, blk, 0, stream>>>(hbuf, Wk + (size_t)l*D_*D_, bk + l*D_, nullptr, kk, N_, D_, D_, 1.0f);
        gemm_kernel<0,false><<<gQ, blk, 0, stream>>>(hbuf, Wv + (size_t)l*D_*D_, bv + l*D_, nullptr, vv, N_, D_, D_, 1.0f);
        rope_kernel<<<gR, blk, 0, stream>>>(q);
        rope_kernel<<<gR, blk, 0, stream>>>(kk);
        attn_kernel<<<B_*H_*S_, blk, 0, stream>>>(q, kk, vv, ob);
        gemm_kernel<0,true ><<<gQ, blk, 0, stream>>>(ob, Wo + (size_t)l*D_*D_, bo + l*D_, x, x, N_, D_, D_, 1.0f);
        ln_kernel<<<N_, blk, 0, stream>>>(x, ln2g + l*D_, ln2b + l*D_, hbuf);
        gemm_kernel<1,false><<<gF1, blk, 0, stream>>>(hbuf, W1 + (size_t)l*FF_*D_, b1 + l*FF_, nullptr, f1, N_, D_, FF_, 1.0f);
        gemm_kernel<0,true ><<<gQ, blk, 0, stream>>>(f1, W2 + (size_t)l*D_*FF_, b2 + l*D_, x, x, N_, FF_, D_, 1.0f);
    }
    gemm_kernel<0,false><<<gOut, blk, 0, stream>>>(x, Wout, bout, nullptr, out, N_, D_, 64, 1.0f);
}

// Round 2
// 7304.195 us; speedup vs baseline: 2.7374x; 2.7374x over previous
//
#include <hip/hip_runtime.h>
#include <hip/hip_bf16.h>
#include <math.h>

#define S_   1000
#define B_   4
#define D_   1024
#define H_   16
#define HD_  64
#define L_   4
#define FF_  4096
#define N_   (S_*B_)   /* 4000 token rows */

// ---------------- embedding lookup ----------------
__global__ void embed_kernel(const int* __restrict__ tokens,
                             const float* __restrict__ emb,
                             float* __restrict__ x) {
    int n = blockIdx.x;                 // 0..N_-1, n = s*B + b
    int tok = tokens[n];
    const float4* src = (const float4*)(emb + (size_t)tok * D_);
    float4* dst = (float4*)(x + (size_t)n * D_);
    dst[threadIdx.x] = src[threadIdx.x];   // 256 threads * float4 = 1024
}

// ---------------- layernorm (one row per block, 256 thr) ----------------
__global__ __launch_bounds__(256)
void ln_kernel(const float* __restrict__ in,
               const float* __restrict__ g,
               const float* __restrict__ b,
               float* __restrict__ out) {
    int n = blockIdx.x;
    int tid = threadIdx.x;
    const float4* row = (const float4*)(in + (size_t)n * D_);
    float4 v = row[tid];
    float s  = v.x + v.y + v.z + v.w;
    float sq = v.x*v.x + v.y*v.y + v.z*v.z + v.w*v.w;
    #pragma unroll
    for (int off = 32; off; off >>= 1) {
        s  += __shfl_down(s, off);
        sq += __shfl_down(sq, off);
    }
    __shared__ float rs[4], rq[4];
    int wid = tid >> 6;
    if ((tid & 63) == 0) { rs[wid] = s; rq[wid] = sq; }
    __syncthreads();
    s  = rs[0] + rs[1] + rs[2] + rs[3];
    sq = rq[0] + rq[1] + rq[2] + rq[3];
    float mean = s * (1.0f / D_);
    float var  = sq * (1.0f / D_) - mean * mean;
    float rstd = rsqrtf(var + 1e-5f);
    float4 gg = ((const float4*)g)[tid];
    float4 bb = ((const float4*)b)[tid];
    float4 o;
    o.x = (v.x - mean) * rstd * gg.x + bb.x;
    o.y = (v.y - mean) * rstd * gg.y + bb.y;
    o.z = (v.z - mean) * rstd * gg.z + bb.z;
    o.w = (v.w - mean) * rstd * gg.w + bb.w;
    ((float4*)(out + (size_t)n * D_))[tid] = o;
}

// ---------------- fp32 tiled GEMM: C[m,e] = (sum_d A[m,d]*W[e,d] + bias[e])*scale ----------------
template<int ACT, bool RES>
__global__ __launch_bounds__(256)
void gemm_kernel(const float* __restrict__ A,     // [M,K] row-major
                 const float* __restrict__ W,     // [E,K] row-major
                 const float* __restrict__ bias,  // [E]
                 const float* __restrict__ res,   // [M,E] or null
                 float* __restrict__ C,           // [M,E]
                 int M, int K, int E, float scale) {
    __shared__ float As[32][64];
    __shared__ float Ws[32][64];
    int tid = threadIdx.x;
    int m0 = blockIdx.x * 64, e0 = blockIdx.y * 64;
    int tx = tid & 15, ty = tid >> 4;
    int lrow = tid >> 2;          // 0..63
    int lkc  = (tid & 3) * 8;     // 0,8,16,24
    float acc[4][4] = {};
    const float* Arow = A + (size_t)(m0 + lrow) * K + lkc;
    const float* Wrow = W + (size_t)(e0 + lrow) * K + lkc;
    bool aval = (m0 + lrow) < M;

    for (int k0 = 0; k0 < K; k0 += 32) {
        float4 a0 = make_float4(0.f,0.f,0.f,0.f), a1 = a0;
        if (aval) {
            a0 = *(const float4*)(Arow + k0);
            a1 = *(const float4*)(Arow + k0 + 4);
        }
        float4 w0 = *(const float4*)(Wrow + k0);
        float4 w1 = *(const float4*)(Wrow + k0 + 4);
        As[lkc+0][lrow] = a0.x; As[lkc+1][lrow] = a0.y;
        As[lkc+2][lrow] = a0.z; As[lkc+3][lrow] = a0.w;
        As[lkc+4][lrow] = a1.x; As[lkc+5][lrow] = a1.y;
        As[lkc+6][lrow] = a1.z; As[lkc+7][lrow] = a1.w;
        Ws[lkc+0][lrow] = w0.x; Ws[lkc+1][lrow] = w0.y;
        Ws[lkc+2][lrow] = w0.z; Ws[lkc+3][lrow] = w0.w;
        Ws[lkc+4][lrow] = w1.x; Ws[lkc+5][lrow] = w1.y;
        Ws[lkc+6][lrow] = w1.z; Ws[lkc+7][lrow] = w1.w;
        __syncthreads();
        #pragma unroll
        for (int kk = 0; kk < 32; ++kk) {
            float4 a = *(const float4*)(&As[kk][ty*4]);
            float4 w = *(const float4*)(&Ws[kk][tx*4]);
            acc[0][0] += a.x*w.x; acc[0][1] += a.x*w.y; acc[0][2] += a.x*w.z; acc[0][3] += a.x*w.w;
            acc[1][0] += a.y*w.x; acc[1][1] += a.y*w.y; acc[1][2] += a.y*w.z; acc[1][3] += a.y*w.w;
            acc[2][0] += a.z*w.x; acc[2][1] += a.z*w.y; acc[2][2] += a.z*w.z; acc[2][3] += a.z*w.w;
            acc[3][0] += a.w*w.x; acc[3][1] += a.w*w.y; acc[3][2] += a.w*w.z; acc[3][3] += a.w*w.w;
        }
        __syncthreads();
    }
    #pragma unroll
    for (int i = 0; i < 4; ++i) {
        int m = m0 + ty*4 + i;
        if (m >= M) continue;
        #pragma unroll
        for (int j = 0; j < 4; ++j) {
            int e = e0 + tx*4 + j;
            float val = (acc[i][j] + bias[e]) * scale;
            if (ACT == 1) val = 0.5f * val * (1.0f + erff(val * 0.70710678118654752f));
            if (RES) val += res[(size_t)m * E + e];
            C[(size_t)m * E + e] = val;
        }
    }
}

// ---------------- RoPE (in place on q or k, [N, H*HD] layout) ----------------
__global__ void rope_kernel(float* __restrict__ x) {
    int idx = blockIdx.x * 256 + threadIdx.x;   // N_*H_*32 pairs
    if (idx >= N_ * H_ * 32) return;
    int j = idx & 31;
    int h = (idx >> 5) & (H_ - 1);
    int n = idx >> 9;
    int s = n >> 2;                 // n = s*B + b, B=4
    float inv = expf(-(float)j * 0.2878231366242557f);  // ln(10000)/32
    float ang = (float)s * inv;
    float sn, cs;
    sincosf(ang, &sn, &cs);
    float* p = x + (size_t)n * D_ + h * HD_ + j;
    float a = p[0], b = p[32];
    p[0]  = a * cs - b * sn;
    p[32] = b * cs + a * sn;
}

// ---------------- tiled flash attention: 64 queries x one (b,h) per block ----------------
// Qt/Kt: [d][t] transposed, stride 64, 16B-group XOR swizzle (col16 = tg ^ (d>>2))
// Ps:    [q][t] swizzled (col16 = tg ^ (q&15));  Vs: [t][d] plain stride 64.
__global__ __launch_bounds__(256)
void attn_tile_kernel(const float* __restrict__ q, const float* __restrict__ k,
                      const float* __restrict__ v, float* __restrict__ o) {
    __shared__ float Qt[64][64];
    __shared__ float Kt[64][64];
    __shared__ float Ps[64][64];
    __shared__ float Vs[64][64];

    int bid = blockIdx.x;
    int qt_ = bid & 15;           // 16 q-tiles (ceil(1000/64))
    int bh  = bid >> 4;
    int b   = bh >> 4;            // /H_
    int h   = bh & (H_ - 1);
    int tid = threadIdx.x;
    int tx = tid & 15, ty = tid >> 4;
    int q0 = qt_ * 64;

    // ---- stage Q (transposed + swizzled) ----
    #pragma unroll
    for (int rep = 0; rep < 4; ++rep) {
        int idx = rep * 256 + tid;
        int r  = idx >> 4;        // q row in tile (0..63)
        int c4 = idx & 15;        // d group
        int s  = q0 + r;
        float4 val = make_float4(0.f,0.f,0.f,0.f);
        if (s < S_) val = *(const float4*)(q + ((size_t)s*B_ + b)*D_ + h*HD_ + c4*4);
        int cb = (((r >> 2) ^ c4) & 15) * 4 + (r & 3);
        Qt[c4*4+0][cb] = val.x;
        Qt[c4*4+1][cb] = val.y;
        Qt[c4*4+2][cb] = val.z;
        Qt[c4*4+3][cb] = val.w;
    }

    float O[4][4] = {{0.f,0.f,0.f,0.f}};
    float mreg[4] = {-1e30f,-1e30f,-1e30f,-1e30f};
    float lreg[4] = {0.f,0.f,0.f,0.f};
    int qq0 = ty * 4;

    for (int t0 = 0; t0 < S_; t0 += 64) {
        __syncthreads();          // prev PV done; (first iter: Q staged)
        // ---- stage K (transposed+swizzled) and V (plain) ----
        #pragma unroll
        for (int rep = 0; rep < 4; ++rep) {
            int idx = rep * 256 + tid;
            int r  = idx >> 4;
            int c4 = idx & 15;
            int t  = t0 + r;
            float4 kv = make_float4(0.f,0.f,0.f,0.f), vv4 = kv;
            if (t < S_) {
                size_t off = ((size_t)t*B_ + b)*D_ + h*HD_ + c4*4;
                kv  = *(const float4*)(k + off);
                vv4 = *(const float4*)(v + off);
            }
            int cb = (((r >> 2) ^ c4) & 15) * 4 + (r & 3);
            Kt[c4*4+0][cb] = kv.x;
            Kt[c4*4+1][cb] = kv.y;
            Kt[c4*4+2][cb] = kv.z;
            Kt[c4*4+3][cb] = kv.w;
            *(float4*)(&Vs[r][c4*4]) = vv4;
        }
        __syncthreads();
        // ---- scores: outer-product over d ----
        float s_[4][4] = {};
        #pragma unroll 8
        for (int d = 0; d < 64; ++d) {
            int dg = d >> 2;
            float4 qf = *(const float4*)(&Qt[d][((ty ^ dg) & 15) * 4]);
            float4 kf = *(const float4*)(&Kt[d][((tx ^ dg) & 15) * 4]);
            float qa[4] = {qf.x, qf.y, qf.z, qf.w};
            float ka[4] = {kf.x, kf.y, kf.z, kf.w};
            #pragma unroll
            for (int i = 0; i < 4; ++i)
                #pragma unroll
                for (int j = 0; j < 4; ++j)
                    s_[i][j] += qa[i] * ka[j];
        }
        // mask invalid keys
        #pragma unroll
        for (int j = 0; j < 4; ++j)
            if (t0 + tx*4 + j >= S_) {
                s_[0][j] = -1e30f; s_[1][j] = -1e30f;
                s_[2][j] = -1e30f; s_[3][j] = -1e30f;
            }
        // ---- online softmax (all stats in regs, replicated across tx lanes) ----
        #pragma unroll
        for (int i = 0; i < 4; ++i) {
            float rm = fmaxf(fmaxf(s_[i][0], s_[i][1]), fmaxf(s_[i][2], s_[i][3]));
            rm = fmaxf(rm, __shfl_xor(rm, 1));
            rm = fmaxf(rm, __shfl_xor(rm, 2));
            rm = fmaxf(rm, __shfl_xor(rm, 4));
            rm = fmaxf(rm, __shfl_xor(rm, 8));
            float mnew = fmaxf(mreg[i], rm);
            float sc   = __expf(mreg[i] - mnew);
            mreg[i] = mnew;
            float4 pv;
            pv.x = __expf(s_[i][0] - mnew);
            pv.y = __expf(s_[i][1] - mnew);
            pv.z = __expf(s_[i][2] - mnew);
            pv.w = __expf(s_[i][3] - mnew);
            float rs = pv.x + pv.y + pv.z + pv.w;
            rs += __shfl_xor(rs, 1);
            rs += __shfl_xor(rs, 2);
            rs += __shfl_xor(rs, 4);
            rs += __shfl_xor(rs, 8);
            lreg[i] = lreg[i] * sc + rs;
            int qq = qq0 + i;
            *(float4*)(&Ps[qq][((tx ^ (qq & 15)) & 15) * 4]) = pv;
            O[i][0] *= sc; O[i][1] *= sc; O[i][2] *= sc; O[i][3] *= sc;
        }
        __syncthreads();
        // ---- PV: O += P * V ----
        #pragma unroll 4
        for (int t4 = 0; t4 < 16; ++t4) {
            float pa[4][4];
            #pragma unroll
            for (int i = 0; i < 4; ++i) {
                int qq = qq0 + i;
                float4 pf = *(const float4*)(&Ps[qq][((t4 ^ (qq & 15)) & 15) * 4]);
                pa[i][0] = pf.x; pa[i][1] = pf.y; pa[i][2] = pf.z; pa[i][3] = pf.w;
            }
            #pragma unroll
            for (int u = 0; u < 4; ++u) {
                float4 vf = *(const float4*)(&Vs[t4*4+u][tx*4]);
                #pragma unroll
                for (int i = 0; i < 4; ++i) {
                    O[i][0] += pa[i][u] * vf.x;
                    O[i][1] += pa[i][u] * vf.y;
                    O[i][2] += pa[i][u] * vf.z;
                    O[i][3] += pa[i][u] * vf.w;
                }
            }
        }
    }
    // ---- store ----
    #pragma unroll
    for (int i = 0; i < 4; ++i) {
        int s = q0 + qq0 + i;
        if (s >= S_) continue;
        float inv = 1.0f / lreg[i];
        float4 r;
        r.x = O[i][0] * inv; r.y = O[i][1] * inv;
        r.z = O[i][2] * inv; r.w = O[i][3] * inv;
        *(float4*)(o + ((size_t)s*B_ + b)*D_ + h*HD_ + tx*4) = r;
    }
}

extern "C" void kernel_launch(void* const* d_in, const int* in_sizes, int n_in,
                              void* d_out, int out_size, void* d_ws, size_t ws_size,
                              hipStream_t stream) {
    const int*   tokens = (const int*)  d_in[0];
    const float* Wemb   = (const float*)d_in[1];
    const float* Wq     = (const float*)d_in[2];
    const float* bq     = (const float*)d_in[3];
    const float* Wk     = (const float*)d_in[4];
    const float* bk     = (const float*)d_in[5];
    const float* Wv     = (const float*)d_in[6];
    const float* bv     = (const float*)d_in[7];
    const float* Wo     = (const float*)d_in[8];
    const float* bo     = (const float*)d_in[9];
    const float* ln1g   = (const float*)d_in[10];
    const float* ln1b   = (const float*)d_in[11];
    const float* ln2g   = (const float*)d_in[12];
    const float* ln2b   = (const float*)d_in[13];
    const float* W1     = (const float*)d_in[14];
    const float* b1     = (const float*)d_in[15];
    const float* W2     = (const float*)d_in[16];
    const float* b2     = (const float*)d_in[17];
    const float* Wout   = (const float*)d_in[18];
    const float* bout   = (const float*)d_in[19];
    float* out = (float*)d_out;

    float* ws = (float*)d_ws;
    const size_t ND = (size_t)N_ * D_;
    float* x    = ws;
    float* hbuf = x    + ND;
    float* q    = hbuf + ND;
    float* kk   = q    + ND;
    float* vv   = kk   + ND;
    float* ob   = vv   + ND;
    float* f1   = ob   + ND;        // N_*FF_

    dim3 blk(256);
    embed_kernel<<<N_, blk, 0, stream>>>(tokens, Wemb, x);

    const float qscale = 0.125f;    // HD^-0.5
    dim3 gQ((N_ + 63) / 64, D_ / 64);
    dim3 gF1((N_ + 63) / 64, FF_ / 64);
    dim3 gOut((N_ + 63) / 64, 1);
    int rth = N_ * H_ * 32;
    dim3 gR((rth + 255) / 256);
    dim3 gA(16 * B_ * H_);          // 16 q-tiles x (b,h)

    for (int l = 0; l < L_; ++l) {
        ln_kernel<<<N_, blk, 0, stream>>>(x, ln1g + l*D_, ln1b + l*D_, hbuf);
        gemm_kernel<0,false><<<gQ, blk, 0, stream>>>(hbuf, Wq + (size_t)l*D_*D_, bq + l*D_, nullptr, q,  N_, D_, D_, qscale);
        gemm_kernel<0,false><<<gQ, blk, 0, stream>>>(hbuf, Wk + (size_t)l*D_*D_, bk + l*D_, nullptr, kk, N_, D_, D_, 1.0f);
        gemm_kernel<0,false><<<gQ, blk, 0, stream>>>(hbuf, Wv + (size_t)l*D_*D_, bv + l*D_, nullptr, vv, N_, D_, D_, 1.0f);
        rope_kernel<<<gR, blk, 0, stream>>>(q);
        rope_kernel<<<gR, blk, 0, stream>>>(kk);
        attn_tile_kernel<<<gA, blk, 0, stream>>>(q, kk, vv, ob);
        gemm_kernel<0,true ><<<gQ, blk, 0, stream>>>(ob, Wo + (size_t)l*D_*D_, bo + l*D_, x, x, N_, D_, D_, 1.0f);
        ln_kernel<<<N_, blk, 0, stream>>>(x, ln2g + l*D_, ln2b + l*D_, hbuf);
        gemm_kernel<1,false><<<gF1, blk, 0, stream>>>(hbuf, W1 + (size_t)l*FF_*D_, b1 + l*FF_, nullptr, f1, N_, D_, FF_, 1.0f);
        gemm_kernel<0,true ><<<gQ, blk, 0, stream>>>(f1, W2 + (size_t)l*D_*FF_, b2 + l*D_, x, x, N_, FF_, D_, 1.0f);
    }
    gemm_kernel<0,false><<<gOut, blk, 0, stream>>>(x, Wout, bout, nullptr, out, N_, D_, 64, 1.0f);
}

// Round 3
// 2424.747 us; speedup vs baseline: 8.2460x; 3.0124x over previous
//
#include <hip/hip_runtime.h>
#include <hip/hip_bf16.h>
#include <math.h>

#define S_   1000
#define B_   4
#define D_   1024
#define H_   16
#define HD_  64
#define L_   4
#define FF_  4096
#define N_   (S_*B_)   /* 4000 token rows */

typedef __bf16 bf16x8 __attribute__((ext_vector_type(8)));
typedef float  f32x4  __attribute__((ext_vector_type(4)));

__device__ __forceinline__ unsigned short f2b(float f) {
    unsigned u = __builtin_bit_cast(unsigned, f);
    u = (u + 0x7FFFu + ((u >> 16) & 1u)) >> 16;   // RNE
    return (unsigned short)u;
}

__device__ __forceinline__ void gl16(const void* g, void* l) {
    __builtin_amdgcn_global_load_lds(
        (const __attribute__((address_space(1))) unsigned int*)g,
        (__attribute__((address_space(3))) unsigned int*)l, 16, 0, 0);
}

// ---------------- embedding lookup ----------------
__global__ void embed_kernel(const int* __restrict__ tokens,
                             const float* __restrict__ emb,
                             float* __restrict__ x) {
    int n = blockIdx.x;
    int tok = tokens[n];
    const float4* src = (const float4*)(emb + (size_t)tok * D_);
    float4* dst = (float4*)(x + (size_t)n * D_);
    dst[threadIdx.x] = src[threadIdx.x];
}

// ---------------- weight fp32->bf16 conversion (one layer, 12M elems) ----------------
__global__ __launch_bounds__(256)
void cvtw_kernel(const float* __restrict__ wq, const float* __restrict__ wk,
                 const float* __restrict__ wv, const float* __restrict__ wo,
                 const float* __restrict__ w1, const float* __restrict__ w2,
                 unsigned short* __restrict__ dst) {
    const size_t M1 = (size_t)D_ * D_;          // 1M
    const size_t M4 = (size_t)FF_ * D_;         // 4M
    size_t i = ((size_t)blockIdx.x * 256 + threadIdx.x) * 4;
    const float* src; size_t off;
    if      (i < M1)        { src = wq; off = i; }
    else if (i < 2*M1)      { src = wk; off = i - M1; }
    else if (i < 3*M1)      { src = wv; off = i - 2*M1; }
    else if (i < 4*M1)      { src = wo; off = i - 3*M1; }
    else if (i < 4*M1+M4)   { src = w1; off = i - 4*M1; }
    else                    { src = w2; off = i - 4*M1 - M4; }
    float4 v = *(const float4*)(src + off);
    ushort4 u;
    u.x = f2b(v.x); u.y = f2b(v.y); u.z = f2b(v.z); u.w = f2b(v.w);
    *(ushort4*)(dst + i) = u;
}

// ---------------- layernorm: fp32 in, bf16 out ----------------
__global__ __launch_bounds__(256)
void ln_kernel(const float* __restrict__ in,
               const float* __restrict__ g,
               const float* __restrict__ b,
               unsigned short* __restrict__ out) {
    int n = blockIdx.x;
    int tid = threadIdx.x;
    const float4* row = (const float4*)(in + (size_t)n * D_);
    float4 v = row[tid];
    float s  = v.x + v.y + v.z + v.w;
    float sq = v.x*v.x + v.y*v.y + v.z*v.z + v.w*v.w;
    #pragma unroll
    for (int off = 32; off; off >>= 1) {
        s  += __shfl_down(s, off);
        sq += __shfl_down(sq, off);
    }
    __shared__ float rs[4], rq[4];
    int wid = tid >> 6;
    if ((tid & 63) == 0) { rs[wid] = s; rq[wid] = sq; }
    __syncthreads();
    s  = rs[0] + rs[1] + rs[2] + rs[3];
    sq = rq[0] + rq[1] + rq[2] + rq[3];
    float mean = s * (1.0f / D_);
    float var  = sq * (1.0f / D_) - mean * mean;
    float rstd = rsqrtf(var + 1e-5f);
    float4 gg = ((const float4*)g)[tid];
    float4 bb = ((const float4*)b)[tid];
    ushort4 o;
    o.x = f2b((v.x - mean) * rstd * gg.x + bb.x);
    o.y = f2b((v.y - mean) * rstd * gg.y + bb.y);
    o.z = f2b((v.z - mean) * rstd * gg.z + bb.z);
    o.w = f2b((v.w - mean) * rstd * gg.w + bb.w);
    ((ushort4*)(out + (size_t)n * D_))[tid] = o;
}

// ---------------- bf16 MFMA GEMM: C[m,e] = epilogue( sum_d A[m,d]*W[e,d] ) ----------------
// A [M,K] bf16 row-major, W [E,K] bf16 row-major. 128x128 tile, BK=64, 4 waves (2x2).
// LDS: linear dest for global_load_lds; content XOR-swizzled via pre-swizzled SOURCE chunk
// (chunk' = chunk ^ (row&7)); ds_read_b128 applies the same XOR -> conflict-free.
// ACT: 1 = exact GELU. RES: add fp32 residual. OBF: 1 = bf16 output else fp32.
template<int ACT, int RES, int OBF>
__global__ __launch_bounds__(256)
void mgemm_kernel(const unsigned short* __restrict__ A,
                  const unsigned short* __restrict__ W,
                  const float* __restrict__ bias,
                  const float* __restrict__ res,
                  void* __restrict__ Cout,
                  int M, int K, int E, float scale) {
    __shared__ __align__(16) unsigned short As[128 * 64];
    __shared__ __align__(16) unsigned short Ws[128 * 64];
    int tid  = threadIdx.x;
    int w    = tid >> 6;          // wave 0..3
    int lane = tid & 63;
    int wr = w >> 1, wc = w & 1;  // 2x2 wave grid, each 64x64 output
    int m0 = blockIdx.x * 128, e0 = blockIdx.y * 128;

    f32x4 acc[4][4] = {};

    int srow = lane >> 3;                       // 0..7 row within 8-row stripe
    int schunk = ((lane & 7) ^ srow) * 8;       // pre-swizzled source chunk (elems)
    int lrow15 = lane & 15;
    int l7 = lane & 7;

    for (int kt = 0; kt < K; kt += 64) {
        #pragma unroll
        for (int c4 = 0; c4 < 4; ++c4) {
            int r0 = w * 32 + c4 * 8;
            int ar = m0 + r0 + srow; if (ar > M - 1) ar = M - 1;
            gl16(A + (size_t)ar * K + kt + schunk, &As[r0 * 64]);
            int er = e0 + r0 + srow;
            gl16(W + (size_t)er * K + kt + schunk, &Ws[r0 * 64]);
        }
        __syncthreads();
        #pragma unroll
        for (int ks = 0; ks < 2; ++ks) {
            int cc = ks * 4 + (lane >> 4);
            int slot = (cc ^ l7) * 16;          // byte offset of 16B chunk
            bf16x8 av[4], bv[4];
            #pragma unroll
            for (int i = 0; i < 4; ++i)
                av[i] = *(const bf16x8*)((const char*)As + (wr*64 + i*16 + lrow15) * 128 + slot);
            #pragma unroll
            for (int j = 0; j < 4; ++j)
                bv[j] = *(const bf16x8*)((const char*)Ws + (wc*64 + j*16 + lrow15) * 128 + slot);
            #pragma unroll
            for (int i = 0; i < 4; ++i)
                #pragma unroll
                for (int j = 0; j < 4; ++j)
                    acc[i][j] = __builtin_amdgcn_mfma_f32_16x16x32_bf16(av[i], bv[j], acc[i][j], 0, 0, 0);
        }
        __syncthreads();
    }

    // epilogue: C/D layout col=lane&15, row=(lane>>4)*4+reg
    #pragma unroll
    for (int i = 0; i < 4; ++i) {
        int mrow = m0 + wr*64 + i*16 + (lane >> 4) * 4;
        #pragma unroll
        for (int j = 0; j < 4; ++j) {
            int e = e0 + wc*64 + j*16 + lrow15;
            float bval = bias[e];
            #pragma unroll
            for (int r = 0; r < 4; ++r) {
                int m = mrow + r;
                if (m >= M) continue;
                float val = (acc[i][j][r] + bval) * scale;
                if (ACT == 1) val = 0.5f * val * (1.0f + erff(val * 0.70710678118654752f));
                if (RES) val += res[(size_t)m * E + e];
                if (OBF) ((unsigned short*)Cout)[(size_t)m * E + e] = f2b(val);
                else     ((float*)Cout)[(size_t)m * E + e] = val;
            }
        }
    }
}

// ---------------- fp32 tiled GEMM (final 64-col projection only) ----------------
__global__ __launch_bounds__(256)
void gemm_kernel(const float* __restrict__ A, const float* __restrict__ W,
                 const float* __restrict__ bias, float* __restrict__ C,
                 int M, int K, int E) {
    __shared__ float As[32][64];
    __shared__ float Ws[32][64];
    int tid = threadIdx.x;
    int m0 = blockIdx.x * 64, e0 = blockIdx.y * 64;
    int tx = tid & 15, ty = tid >> 4;
    int lrow = tid >> 2;
    int lkc  = (tid & 3) * 8;
    float acc[4][4] = {};
    const float* Arow = A + (size_t)(m0 + lrow) * K + lkc;
    const float* Wrow = W + (size_t)(e0 + lrow) * K + lkc;
    bool aval = (m0 + lrow) < M;

    for (int k0 = 0; k0 < K; k0 += 32) {
        float4 a0 = make_float4(0.f,0.f,0.f,0.f), a1 = a0;
        if (aval) {
            a0 = *(const float4*)(Arow + k0);
            a1 = *(const float4*)(Arow + k0 + 4);
        }
        float4 w0 = *(const float4*)(Wrow + k0);
        float4 w1 = *(const float4*)(Wrow + k0 + 4);
        As[lkc+0][lrow] = a0.x; As[lkc+1][lrow] = a0.y;
        As[lkc+2][lrow] = a0.z; As[lkc+3][lrow] = a0.w;
        As[lkc+4][lrow] = a1.x; As[lkc+5][lrow] = a1.y;
        As[lkc+6][lrow] = a1.z; As[lkc+7][lrow] = a1.w;
        Ws[lkc+0][lrow] = w0.x; Ws[lkc+1][lrow] = w0.y;
        Ws[lkc+2][lrow] = w0.z; Ws[lkc+3][lrow] = w0.w;
        Ws[lkc+4][lrow] = w1.x; Ws[lkc+5][lrow] = w1.y;
        Ws[lkc+6][lrow] = w1.z; Ws[lkc+7][lrow] = w1.w;
        __syncthreads();
        #pragma unroll
        for (int kk = 0; kk < 32; ++kk) {
            float4 a = *(const float4*)(&As[kk][ty*4]);
            float4 ww = *(const float4*)(&Ws[kk][tx*4]);
            acc[0][0] += a.x*ww.x; acc[0][1] += a.x*ww.y; acc[0][2] += a.x*ww.z; acc[0][3] += a.x*ww.w;
            acc[1][0] += a.y*ww.x; acc[1][1] += a.y*ww.y; acc[1][2] += a.y*ww.z; acc[1][3] += a.y*ww.w;
            acc[2][0] += a.z*ww.x; acc[2][1] += a.z*ww.y; acc[2][2] += a.z*ww.z; acc[2][3] += a.z*ww.w;
            acc[3][0] += a.w*ww.x; acc[3][1] += a.w*ww.y; acc[3][2] += a.w*ww.z; acc[3][3] += a.w*ww.w;
        }
        __syncthreads();
    }
    #pragma unroll
    for (int i = 0; i < 4; ++i) {
        int m = m0 + ty*4 + i;
        if (m >= M) continue;
        #pragma unroll
        for (int j = 0; j < 4; ++j) {
            int e = e0 + tx*4 + j;
            C[(size_t)m * E + e] = acc[i][j] + bias[e];
        }
    }
}

// ---------------- RoPE (in place on q or k, fp32) ----------------
__global__ void rope_kernel(float* __restrict__ x) {
    int idx = blockIdx.x * 256 + threadIdx.x;
    if (idx >= N_ * H_ * 32) return;
    int j = idx & 31;
    int h = (idx >> 5) & (H_ - 1);
    int n = idx >> 9;
    int s = n >> 2;
    float inv = expf(-(float)j * 0.2878231366242557f);
    float ang = (float)s * inv;
    float sn, cs;
    sincosf(ang, &sn, &cs);
    float* p = x + (size_t)n * D_ + h * HD_ + j;
    float a = p[0], b = p[32];
    p[0]  = a * cs - b * sn;
    p[32] = b * cs + a * sn;
}

// ---------------- tiled flash attention (fp32 math, bf16 out) ----------------
__global__ __launch_bounds__(256)
void attn_tile_kernel(const float* __restrict__ q, const float* __restrict__ k,
                      const float* __restrict__ v, unsigned short* __restrict__ o) {
    __shared__ float Qt[64][64];
    __shared__ float Kt[64][64];
    __shared__ float Ps[64][64];
    __shared__ float Vs[64][64];

    int bid = blockIdx.x;
    int qt_ = bid & 15;
    int bh  = bid >> 4;
    int b   = bh >> 4;
    int h   = bh & (H_ - 1);
    int tid = threadIdx.x;
    int tx = tid & 15, ty = tid >> 4;
    int q0 = qt_ * 64;

    #pragma unroll
    for (int rep = 0; rep < 4; ++rep) {
        int idx = rep * 256 + tid;
        int r  = idx >> 4;
        int c4 = idx & 15;
        int s  = q0 + r;
        float4 val = make_float4(0.f,0.f,0.f,0.f);
        if (s < S_) val = *(const float4*)(q + ((size_t)s*B_ + b)*D_ + h*HD_ + c4*4);
        int cb = (((r >> 2) ^ c4) & 15) * 4 + (r & 3);
        Qt[c4*4+0][cb] = val.x;
        Qt[c4*4+1][cb] = val.y;
        Qt[c4*4+2][cb] = val.z;
        Qt[c4*4+3][cb] = val.w;
    }

    float O[4][4] = {{0.f,0.f,0.f,0.f}};
    float mreg[4] = {-1e30f,-1e30f,-1e30f,-1e30f};
    float lreg[4] = {0.f,0.f,0.f,0.f};
    int qq0 = ty * 4;

    for (int t0 = 0; t0 < S_; t0 += 64) {
        __syncthreads();
        #pragma unroll
        for (int rep = 0; rep < 4; ++rep) {
            int idx = rep * 256 + tid;
            int r  = idx >> 4;
            int c4 = idx & 15;
            int t  = t0 + r;
            float4 kv = make_float4(0.f,0.f,0.f,0.f), vv4 = kv;
            if (t < S_) {
                size_t off = ((size_t)t*B_ + b)*D_ + h*HD_ + c4*4;
                kv  = *(const float4*)(k + off);
                vv4 = *(const float4*)(v + off);
            }
            int cb = (((r >> 2) ^ c4) & 15) * 4 + (r & 3);
            Kt[c4*4+0][cb] = kv.x;
            Kt[c4*4+1][cb] = kv.y;
            Kt[c4*4+2][cb] = kv.z;
            Kt[c4*4+3][cb] = kv.w;
            *(float4*)(&Vs[r][c4*4]) = vv4;
        }
        __syncthreads();
        float s_[4][4] = {};
        #pragma unroll 8
        for (int d = 0; d < 64; ++d) {
            int dg = d >> 2;
            float4 qf = *(const float4*)(&Qt[d][((ty ^ dg) & 15) * 4]);
            float4 kf = *(const float4*)(&Kt[d][((tx ^ dg) & 15) * 4]);
            float qa[4] = {qf.x, qf.y, qf.z, qf.w};
            float ka[4] = {kf.x, kf.y, kf.z, kf.w};
            #pragma unroll
            for (int i = 0; i < 4; ++i)
                #pragma unroll
                for (int j = 0; j < 4; ++j)
                    s_[i][j] += qa[i] * ka[j];
        }
        #pragma unroll
        for (int j = 0; j < 4; ++j)
            if (t0 + tx*4 + j >= S_) {
                s_[0][j] = -1e30f; s_[1][j] = -1e30f;
                s_[2][j] = -1e30f; s_[3][j] = -1e30f;
            }
        #pragma unroll
        for (int i = 0; i < 4; ++i) {
            float rm = fmaxf(fmaxf(s_[i][0], s_[i][1]), fmaxf(s_[i][2], s_[i][3]));
            rm = fmaxf(rm, __shfl_xor(rm, 1));
            rm = fmaxf(rm, __shfl_xor(rm, 2));
            rm = fmaxf(rm, __shfl_xor(rm, 4));
            rm = fmaxf(rm, __shfl_xor(rm, 8));
            float mnew = fmaxf(mreg[i], rm);
            float sc   = __expf(mreg[i] - mnew);
            mreg[i] = mnew;
            float4 pv;
            pv.x = __expf(s_[i][0] - mnew);
            pv.y = __expf(s_[i][1] - mnew);
            pv.z = __expf(s_[i][2] - mnew);
            pv.w = __expf(s_[i][3] - mnew);
            float rsum = pv.x + pv.y + pv.z + pv.w;
            rsum += __shfl_xor(rsum, 1);
            rsum += __shfl_xor(rsum, 2);
            rsum += __shfl_xor(rsum, 4);
            rsum += __shfl_xor(rsum, 8);
            lreg[i] = lreg[i] * sc + rsum;
            int qq = qq0 + i;
            *(float4*)(&Ps[qq][((tx ^ (qq & 15)) & 15) * 4]) = pv;
            O[i][0] *= sc; O[i][1] *= sc; O[i][2] *= sc; O[i][3] *= sc;
        }
        __syncthreads();
        #pragma unroll 4
        for (int t4 = 0; t4 < 16; ++t4) {
            float pa[4][4];
            #pragma unroll
            for (int i = 0; i < 4; ++i) {
                int qq = qq0 + i;
                float4 pf = *(const float4*)(&Ps[qq][((t4 ^ (qq & 15)) & 15) * 4]);
                pa[i][0] = pf.x; pa[i][1] = pf.y; pa[i][2] = pf.z; pa[i][3] = pf.w;
            }
            #pragma unroll
            for (int u = 0; u < 4; ++u) {
                float4 vf = *(const float4*)(&Vs[t4*4+u][tx*4]);
                #pragma unroll
                for (int i = 0; i < 4; ++i) {
                    O[i][0] += pa[i][u] * vf.x;
                    O[i][1] += pa[i][u] * vf.y;
                    O[i][2] += pa[i][u] * vf.z;
                    O[i][3] += pa[i][u] * vf.w;
                }
            }
        }
    }
    #pragma unroll
    for (int i = 0; i < 4; ++i) {
        int s = q0 + qq0 + i;
        if (s >= S_) continue;
        float inv = 1.0f / lreg[i];
        ushort4 r;
        r.x = f2b(O[i][0] * inv); r.y = f2b(O[i][1] * inv);
        r.z = f2b(O[i][2] * inv); r.w = f2b(O[i][3] * inv);
        *(ushort4*)(o + ((size_t)s*B_ + b)*D_ + h*HD_ + tx*4) = r;
    }
}

extern "C" void kernel_launch(void* const* d_in, const int* in_sizes, int n_in,
                              void* d_out, int out_size, void* d_ws, size_t ws_size,
                              hipStream_t stream) {
    const int*   tokens = (const int*)  d_in[0];
    const float* Wemb   = (const float*)d_in[1];
    const float* Wq     = (const float*)d_in[2];
    const float* bq     = (const float*)d_in[3];
    const float* Wk     = (const float*)d_in[4];
    const float* bk     = (const float*)d_in[5];
    const float* Wv     = (const float*)d_in[6];
    const float* bv     = (const float*)d_in[7];
    const float* Wo     = (const float*)d_in[8];
    const float* bo     = (const float*)d_in[9];
    const float* ln1g   = (const float*)d_in[10];
    const float* ln1b   = (const float*)d_in[11];
    const float* ln2g   = (const float*)d_in[12];
    const float* ln2b   = (const float*)d_in[13];
    const float* W1     = (const float*)d_in[14];
    const float* b1     = (const float*)d_in[15];
    const float* W2     = (const float*)d_in[16];
    const float* b2     = (const float*)d_in[17];
    const float* Wout   = (const float*)d_in[18];
    const float* bout   = (const float*)d_in[19];
    float* out = (float*)d_out;

    const size_t ND = (size_t)N_ * D_;      // 4,096,000
    const size_t NF = (size_t)N_ * FF_;     // 16,384,000
    const size_t M1 = (size_t)D_ * D_;
    const size_t M4 = (size_t)FF_ * D_;

    float* x  = (float*)d_ws;
    float* q  = x  + ND;
    float* kk = q  + ND;
    float* vv = kk + ND;
    unsigned short* hb = (unsigned short*)(vv + ND);
    unsigned short* ob = hb + ND;
    unsigned short* f1 = ob + ND;
    unsigned short* wb = f1 + NF;           // 12M bf16 per-layer weights

    dim3 blk(256);
    embed_kernel<<<N_, blk, 0, stream>>>(tokens, Wemb, x);

    dim3 gD(32, 8);    // (4000/128 ceil, 1024/128)
    dim3 gF(32, 32);   // W1: E=4096
    dim3 gCv(12288);   // 12M elems / 4 / 256
    int rth = N_ * H_ * 32;
    dim3 gR((rth + 255) / 256);
    dim3 gA(16 * B_ * H_);
    dim3 gOut((N_ + 63) / 64, 1);

    for (int l = 0; l < L_; ++l) {
        cvtw_kernel<<<gCv, blk, 0, stream>>>(Wq + l*M1, Wk + l*M1, Wv + l*M1,
                                             Wo + l*M1, W1 + l*M4, W2 + l*M4, wb);
        ln_kernel<<<N_, blk, 0, stream>>>(x, ln1g + l*D_, ln1b + l*D_, hb);
        mgemm_kernel<0,0,0><<<gD, blk, 0, stream>>>(hb, wb,        bq + l*D_,  nullptr, q,  N_, D_,  D_,  0.125f);
        mgemm_kernel<0,0,0><<<gD, blk, 0, stream>>>(hb, wb + M1,   bk + l*D_,  nullptr, kk, N_, D_,  D_,  1.0f);
        mgemm_kernel<0,0,0><<<gD, blk, 0, stream>>>(hb, wb + 2*M1, bv + l*D_,  nullptr, vv, N_, D_,  D_,  1.0f);
        rope_kernel<<<gR, blk, 0, stream>>>(q);
        rope_kernel<<<gR, blk, 0, stream>>>(kk);
        attn_tile_kernel<<<gA, blk, 0, stream>>>(q, kk, vv, ob);
        mgemm_kernel<0,1,0><<<gD, blk, 0, stream>>>(ob, wb + 3*M1, bo + l*D_,  x, x,  N_, D_,  D_,  1.0f);
        ln_kernel<<<N_, blk, 0, stream>>>(x, ln2g + l*D_, ln2b + l*D_, hb);
        mgemm_kernel<1,0,1><<<gF, blk, 0, stream>>>(hb, wb + 4*M1, b1 + l*FF_, nullptr, f1, N_, D_,  FF_, 1.0f);
        mgemm_kernel<0,1,0><<<gD, blk, 0, stream>>>(f1, wb + 4*M1 + M4, b2 + l*D_, x, x, N_, FF_, D_,  1.0f);
    }
    gemm_kernel<<<gOut, blk, 0, stream>>>(x, Wout, bout, out, N_, D_, 64);
}

// Round 4
// 1555.278 us; speedup vs baseline: 12.8559x; 1.5590x over previous
//
#include <hip/hip_runtime.h>
#include <hip/hip_bf16.h>
#include <math.h>

#define S_   1000
#define B_   4
#define D_   1024
#define H_   16
#define HD_  64
#define L_   4
#define FF_  4096
#define N_   (S_*B_)   /* 4000 token rows */

typedef __bf16 bf16x8 __attribute__((ext_vector_type(8)));
typedef float  f32x4  __attribute__((ext_vector_type(4)));

__device__ __forceinline__ unsigned short f2b(float f) {
    unsigned u = __builtin_bit_cast(unsigned, f);
    u = (u + 0x7FFFu + ((u >> 16) & 1u)) >> 16;   // RNE
    return (unsigned short)u;
}

__device__ __forceinline__ void gl16(const void* g, void* l) {
    __builtin_amdgcn_global_load_lds(
        (const __attribute__((address_space(1))) unsigned int*)g,
        (__attribute__((address_space(3))) unsigned int*)l, 16, 0, 0);
}

// ---------------- embedding lookup ----------------
__global__ void embed_kernel(const int* __restrict__ tokens,
                             const float* __restrict__ emb,
                             float* __restrict__ x) {
    int n = blockIdx.x;
    int tok = tokens[n];
    const float4* src = (const float4*)(emb + (size_t)tok * D_);
    float4* dst = (float4*)(x + (size_t)n * D_);
    dst[threadIdx.x] = src[threadIdx.x];
}

// ---------------- weight fp32->bf16 conversion (one layer, 12M elems) ----------------
__global__ __launch_bounds__(256)
void cvtw_kernel(const float* __restrict__ wq, const float* __restrict__ wk,
                 const float* __restrict__ wv, const float* __restrict__ wo,
                 const float* __restrict__ w1, const float* __restrict__ w2,
                 unsigned short* __restrict__ dst) {
    const size_t M1 = (size_t)D_ * D_;
    const size_t M4 = (size_t)FF_ * D_;
    size_t i = ((size_t)blockIdx.x * 256 + threadIdx.x) * 4;
    const float* src; size_t off;
    if      (i < M1)        { src = wq; off = i; }
    else if (i < 2*M1)      { src = wk; off = i - M1; }
    else if (i < 3*M1)      { src = wv; off = i - 2*M1; }
    else if (i < 4*M1)      { src = wo; off = i - 3*M1; }
    else if (i < 4*M1+M4)   { src = w1; off = i - 4*M1; }
    else                    { src = w2; off = i - 4*M1 - M4; }
    float4 v = *(const float4*)(src + off);
    ushort4 u;
    u.x = f2b(v.x); u.y = f2b(v.y); u.z = f2b(v.z); u.w = f2b(v.w);
    *(ushort4*)(dst + i) = u;
}

// ---------------- layernorm: fp32 in, bf16 out ----------------
__global__ __launch_bounds__(256)
void ln_kernel(const float* __restrict__ in,
               const float* __restrict__ g,
               const float* __restrict__ b,
               unsigned short* __restrict__ out) {
    int n = blockIdx.x;
    int tid = threadIdx.x;
    const float4* row = (const float4*)(in + (size_t)n * D_);
    float4 v = row[tid];
    float s  = v.x + v.y + v.z + v.w;
    float sq = v.x*v.x + v.y*v.y + v.z*v.z + v.w*v.w;
    #pragma unroll
    for (int off = 32; off; off >>= 1) {
        s  += __shfl_down(s, off);
        sq += __shfl_down(sq, off);
    }
    __shared__ float rs[4], rq[4];
    int wid = tid >> 6;
    if ((tid & 63) == 0) { rs[wid] = s; rq[wid] = sq; }
    __syncthreads();
    s  = rs[0] + rs[1] + rs[2] + rs[3];
    sq = rq[0] + rq[1] + rq[2] + rq[3];
    float mean = s * (1.0f / D_);
    float var  = sq * (1.0f / D_) - mean * mean;
    float rstd = rsqrtf(var + 1e-5f);
    float4 gg = ((const float4*)g)[tid];
    float4 bb = ((const float4*)b)[tid];
    ushort4 o;
    o.x = f2b((v.x - mean) * rstd * gg.x + bb.x);
    o.y = f2b((v.y - mean) * rstd * gg.y + bb.y);
    o.z = f2b((v.z - mean) * rstd * gg.z + bb.z);
    o.w = f2b((v.w - mean) * rstd * gg.w + bb.w);
    ((ushort4*)(out + (size_t)n * D_))[tid] = o;
}

// ---------------- bf16 MFMA GEMM (128x128 tile, BK=64, 4 waves 2x2) ----------------
template<int ACT, int RES, int OBF>
__global__ __launch_bounds__(256)
void mgemm_kernel(const unsigned short* __restrict__ A,
                  const unsigned short* __restrict__ W,
                  const float* __restrict__ bias,
                  const float* __restrict__ res,
                  void* __restrict__ Cout,
                  int M, int K, int E, float scale) {
    __shared__ __align__(16) unsigned short As[128 * 64];
    __shared__ __align__(16) unsigned short Ws[128 * 64];
    int tid  = threadIdx.x;
    int w    = tid >> 6;
    int lane = tid & 63;
    int wr = w >> 1, wc = w & 1;
    int m0 = blockIdx.x * 128, e0 = blockIdx.y * 128;

    f32x4 acc[4][4] = {};

    int srow = lane >> 3;
    int schunk = ((lane & 7) ^ srow) * 8;
    int lrow15 = lane & 15;
    int l7 = lane & 7;

    for (int kt = 0; kt < K; kt += 64) {
        #pragma unroll
        for (int c4 = 0; c4 < 4; ++c4) {
            int r0 = w * 32 + c4 * 8;
            int ar = m0 + r0 + srow; if (ar > M - 1) ar = M - 1;
            gl16(A + (size_t)ar * K + kt + schunk, &As[r0 * 64]);
            int er = e0 + r0 + srow;
            gl16(W + (size_t)er * K + kt + schunk, &Ws[r0 * 64]);
        }
        __syncthreads();
        #pragma unroll
        for (int ks = 0; ks < 2; ++ks) {
            int cc = ks * 4 + (lane >> 4);
            int slot = (cc ^ l7) * 16;
            bf16x8 av[4], bv[4];
            #pragma unroll
            for (int i = 0; i < 4; ++i)
                av[i] = *(const bf16x8*)((const char*)As + (wr*64 + i*16 + lrow15) * 128 + slot);
            #pragma unroll
            for (int j = 0; j < 4; ++j)
                bv[j] = *(const bf16x8*)((const char*)Ws + (wc*64 + j*16 + lrow15) * 128 + slot);
            #pragma unroll
            for (int i = 0; i < 4; ++i)
                #pragma unroll
                for (int j = 0; j < 4; ++j)
                    acc[i][j] = __builtin_amdgcn_mfma_f32_16x16x32_bf16(av[i], bv[j], acc[i][j], 0, 0, 0);
        }
        __syncthreads();
    }

    #pragma unroll
    for (int i = 0; i < 4; ++i) {
        int mrow = m0 + wr*64 + i*16 + (lane >> 4) * 4;
        #pragma unroll
        for (int j = 0; j < 4; ++j) {
            int e = e0 + wc*64 + j*16 + lrow15;
            float bval = bias[e];
            #pragma unroll
            for (int r = 0; r < 4; ++r) {
                int m = mrow + r;
                if (m >= M) continue;
                float val = (acc[i][j][r] + bval) * scale;
                if (ACT == 1) val = 0.5f * val * (1.0f + erff(val * 0.70710678118654752f));
                if (RES) val += res[(size_t)m * E + e];
                if (OBF) ((unsigned short*)Cout)[(size_t)m * E + e] = f2b(val);
                else     ((float*)Cout)[(size_t)m * E + e] = val;
            }
        }
    }
}

// ---------------- fp32 tiled GEMM (final 64-col projection only) ----------------
__global__ __launch_bounds__(256)
void gemm_kernel(const float* __restrict__ A, const float* __restrict__ W,
                 const float* __restrict__ bias, float* __restrict__ C,
                 int M, int K, int E) {
    __shared__ float As[32][64];
    __shared__ float Ws[32][64];
    int tid = threadIdx.x;
    int m0 = blockIdx.x * 64, e0 = blockIdx.y * 64;
    int tx = tid & 15, ty = tid >> 4;
    int lrow = tid >> 2;
    int lkc  = (tid & 3) * 8;
    float acc[4][4] = {};
    const float* Arow = A + (size_t)(m0 + lrow) * K + lkc;
    const float* Wrow = W + (size_t)(e0 + lrow) * K + lkc;
    bool aval = (m0 + lrow) < M;

    for (int k0 = 0; k0 < K; k0 += 32) {
        float4 a0 = make_float4(0.f,0.f,0.f,0.f), a1 = a0;
        if (aval) {
            a0 = *(const float4*)(Arow + k0);
            a1 = *(const float4*)(Arow + k0 + 4);
        }
        float4 w0 = *(const float4*)(Wrow + k0);
        float4 w1 = *(const float4*)(Wrow + k0 + 4);
        As[lkc+0][lrow] = a0.x; As[lkc+1][lrow] = a0.y;
        As[lkc+2][lrow] = a0.z; As[lkc+3][lrow] = a0.w;
        As[lkc+4][lrow] = a1.x; As[lkc+5][lrow] = a1.y;
        As[lkc+6][lrow] = a1.z; As[lkc+7][lrow] = a1.w;
        Ws[lkc+0][lrow] = w0.x; Ws[lkc+1][lrow] = w0.y;
        Ws[lkc+2][lrow] = w0.z; Ws[lkc+3][lrow] = w0.w;
        Ws[lkc+4][lrow] = w1.x; Ws[lkc+5][lrow] = w1.y;
        Ws[lkc+6][lrow] = w1.z; Ws[lkc+7][lrow] = w1.w;
        __syncthreads();
        #pragma unroll
        for (int kk = 0; kk < 32; ++kk) {
            float4 a = *(const float4*)(&As[kk][ty*4]);
            float4 ww = *(const float4*)(&Ws[kk][tx*4]);
            acc[0][0] += a.x*ww.x; acc[0][1] += a.x*ww.y; acc[0][2] += a.x*ww.z; acc[0][3] += a.x*ww.w;
            acc[1][0] += a.y*ww.x; acc[1][1] += a.y*ww.y; acc[1][2] += a.y*ww.z; acc[1][3] += a.y*ww.w;
            acc[2][0] += a.z*ww.x; acc[2][1] += a.z*ww.y; acc[2][2] += a.z*ww.z; acc[2][3] += a.z*ww.w;
            acc[3][0] += a.w*ww.x; acc[3][1] += a.w*ww.y; acc[3][2] += a.w*ww.z; acc[3][3] += a.w*ww.w;
        }
        __syncthreads();
    }
    #pragma unroll
    for (int i = 0; i < 4; ++i) {
        int m = m0 + ty*4 + i;
        if (m >= M) continue;
        #pragma unroll
        for (int j = 0; j < 4; ++j) {
            int e = e0 + tx*4 + j;
            C[(size_t)m * E + e] = acc[i][j] + bias[e];
        }
    }
}

// ---------------- RoPE fp32 -> bf16 ----------------
__global__ void ropecvt_kernel(const float* __restrict__ xin,
                               unsigned short* __restrict__ xout) {
    int idx = blockIdx.x * 256 + threadIdx.x;
    if (idx >= N_ * H_ * 32) return;
    int j = idx & 31;
    int h = (idx >> 5) & (H_ - 1);
    int n = idx >> 9;
    int s = n >> 2;
    float inv = __expf(-(float)j * 0.2878231366242557f);  // ln(10000)/32
    float ang = (float)s * inv;
    float sn, cs;
    __sincosf(ang, &sn, &cs);
    const float* p = xin + (size_t)n * D_ + h * HD_ + j;
    unsigned short* q = xout + (size_t)n * D_ + h * HD_ + j;
    float a = p[0], c = p[32];
    q[0]  = f2b(a * cs - c * sn);
    q[32] = f2b(c * cs + a * sn);
}

// ---------------- V transpose: [s][b][h*64+d] bf16 -> [bh][d][1024] bf16 (zero-padded t) ----------------
__global__ __launch_bounds__(256)
void vtr_kernel(const unsigned short* __restrict__ vin,
                unsigned short* __restrict__ vout) {
    __shared__ unsigned short T[64][65];
    int tt = blockIdx.x;       // t-tile 0..15
    int bh = blockIdx.y;       // 0..63
    int b = bh >> 4, h = bh & 15;
    int tid = threadIdx.x;
    #pragma unroll
    for (int rep = 0; rep < 2; ++rep) {
        int slot = rep * 256 + tid;          // 0..511
        int r = slot >> 3, ch = slot & 7;
        int t = tt * 64 + r;
        unsigned short e[8] = {0,0,0,0,0,0,0,0};
        if (t < S_) {
            const unsigned short* src = vin + ((size_t)t * B_ + b) * D_ + h * HD_ + ch * 8;
            *(ushort4*)&e[0] = *(const ushort4*)(src);
            *(ushort4*)&e[4] = *(const ushort4*)(src + 4);
        }
        #pragma unroll
        for (int u = 0; u < 8; ++u) T[r][ch*8+u] = e[u];
    }
    __syncthreads();
    #pragma unroll
    for (int rep = 0; rep < 2; ++rep) {
        int slot = rep * 256 + tid;
        int d = slot >> 3, ch = slot & 7;
        unsigned short e[8];
        #pragma unroll
        for (int u = 0; u < 8; ++u) e[u] = T[ch*8+u][d];
        unsigned short* dst = vout + ((size_t)bh * 64 + d) * 1024 + tt * 64 + ch * 8;
        *(ushort4*)(dst)     = *(ushort4*)&e[0];
        *(ushort4*)(dst + 4) = *(ushort4*)&e[4];
    }
}

// ---------------- bf16 MFMA flash attention ----------------
// Block: 64 queries x one (b,h); 4 waves x 16 q-rows. KV tile = 64.
// K tile [t][d] and Vt tile [d][t] staged via global_load_lds with pre-swizzled
// source chunks (content[row][c] = global[row][c ^ (row&7)]); reads apply same XOR.
// P roundtrip through per-wave swizzled LDS (C-layout write -> A-layout read).
__global__ __launch_bounds__(256)
void mattn_kernel(const unsigned short* __restrict__ qg,
                  const unsigned short* __restrict__ kg,
                  const unsigned short* __restrict__ vt,
                  unsigned short* __restrict__ o) {
    __shared__ __align__(16) unsigned short Ks[64 * 64];
    __shared__ __align__(16) unsigned short Vs[64 * 64];
    __shared__ __align__(16) unsigned short Ps[4][16 * 64];

    int bid = blockIdx.x;
    int qt = bid & 15;            // 16 q-tiles of 64
    int bh = bid >> 4;
    int b = bh >> 4, h = bh & 15;
    int tid = threadIdx.x;
    int w = tid >> 6, lane = tid & 63;
    int l15 = lane & 15, l4 = lane >> 4, l7 = lane & 7;
    int q0 = qt * 64 + w * 16;

    int srow = lane >> 3;
    int schunk = ((lane & 7) ^ srow) * 8;

    // Q A-frags (row = l15, k-chunk = ks*4 + l4 within the 64-d head)
    bf16x8 qfr[2];
    {
        int qr = q0 + l15; if (qr > S_ - 1) qr = S_ - 1;
        const unsigned short* qrow = qg + ((size_t)qr * B_ + b) * D_ + h * HD_;
        qfr[0] = *(const bf16x8*)(qrow + l4 * 8);
        qfr[1] = *(const bf16x8*)(qrow + 32 + l4 * 8);
    }

    f32x4 accO[4] = {};
    float mreg[4] = {-1e30f, -1e30f, -1e30f, -1e30f};
    float lreg[4] = {0.f, 0.f, 0.f, 0.f};

    for (int t0 = 0; t0 < 1024; t0 += 64) {
        __syncthreads();
        #pragma unroll
        for (int c = 0; c < 2; ++c) {
            int r0 = w * 16 + c * 8;
            int tr = t0 + r0 + srow; if (tr > S_ - 1) tr = S_ - 1;
            gl16(kg + ((size_t)tr * B_ + b) * D_ + h * HD_ + schunk, &Ks[r0 * 64]);
            gl16(vt + ((size_t)bh * 64 + r0 + srow) * 1024 + t0 + schunk, &Vs[r0 * 64]);
        }
        __syncthreads();

        // ---- QK^T: s[j] covers t-cols j*16 + l15 ----
        f32x4 s[4] = {};
        #pragma unroll
        for (int ks = 0; ks < 2; ++ks) {
            int cc = ks * 4 + l4;
            int slot = (cc ^ l7) * 16;
            #pragma unroll
            for (int j = 0; j < 4; ++j) {
                bf16x8 kf = *(const bf16x8*)((const char*)Ks + (j*16 + l15) * 128 + slot);
                s[j] = __builtin_amdgcn_mfma_f32_16x16x32_bf16(qfr[ks], kf, s[j], 0, 0, 0);
            }
        }
        // ---- mask invalid t ----
        #pragma unroll
        for (int j = 0; j < 4; ++j) {
            int t = t0 + j * 16 + l15;
            if (t >= S_) { s[j][0] = -1e30f; s[j][1] = -1e30f; s[j][2] = -1e30f; s[j][3] = -1e30f; }
        }
        // ---- online softmax (row r = l4*4 + r within wave's 16 q-rows) ----
        float rm[4], sc[4], rsum[4];
        #pragma unroll
        for (int r = 0; r < 4; ++r)
            rm[r] = fmaxf(fmaxf(s[0][r], s[1][r]), fmaxf(s[2][r], s[3][r]));
        #pragma unroll
        for (int mk = 1; mk <= 8; mk <<= 1) {
            #pragma unroll
            for (int r = 0; r < 4; ++r) rm[r] = fmaxf(rm[r], __shfl_xor(rm[r], mk));
        }
        #pragma unroll
        for (int r = 0; r < 4; ++r) {
            float mn = fmaxf(mreg[r], rm[r]);
            sc[r] = __expf(mreg[r] - mn);
            mreg[r] = mn;
            rsum[r] = 0.f;
        }
        #pragma unroll
        for (int j = 0; j < 4; ++j) {
            int inb = (j * 16 + l15) * 2;
            #pragma unroll
            for (int r = 0; r < 4; ++r) {
                float p = __expf(s[j][r] - mreg[r]);
                rsum[r] += p;
                int row = l4 * 4 + r;
                *(unsigned short*)((char*)&Ps[w][0] + row * 128 +
                    ((((inb >> 4) ^ (row & 7)) << 4)) + (inb & 15)) = f2b(p);
            }
        }
        #pragma unroll
        for (int mk = 1; mk <= 8; mk <<= 1) {
            #pragma unroll
            for (int r = 0; r < 4; ++r) rsum[r] += __shfl_xor(rsum[r], mk);
        }
        #pragma unroll
        for (int r = 0; r < 4; ++r) lreg[r] = lreg[r] * sc[r] + rsum[r];
        #pragma unroll
        for (int j = 0; j < 4; ++j) {
            accO[j][0] *= sc[0]; accO[j][1] *= sc[1];
            accO[j][2] *= sc[2]; accO[j][3] *= sc[3];
        }
        // ---- PV: A = Ps (16 q-rows x 64 t), B = Vs (64 d-rows x 64 t) ----
        #pragma unroll
        for (int ks = 0; ks < 2; ++ks) {
            int cc = ks * 4 + l4;
            int slot = (cc ^ l7) * 16;
            bf16x8 pf = *(const bf16x8*)((const char*)&Ps[w][0] + l15 * 128 + slot);
            #pragma unroll
            for (int j = 0; j < 4; ++j) {
                bf16x8 vf = *(const bf16x8*)((const char*)Vs + (j*16 + l15) * 128 + slot);
                accO[j] = __builtin_amdgcn_mfma_f32_16x16x32_bf16(pf, vf, accO[j], 0, 0, 0);
            }
        }
    }
    // ---- epilogue ----
    #pragma unroll
    for (int r = 0; r < 4; ++r) {
        int q = q0 + l4 * 4 + r;
        if (q >= S_) continue;
        float inv = 1.0f / lreg[r];
        unsigned short* orow = o + ((size_t)q * B_ + b) * D_ + h * HD_;
        #pragma unroll
        for (int j = 0; j < 4; ++j)
            orow[j * 16 + l15] = f2b(accO[j][r] * inv);
    }
}

extern "C" void kernel_launch(void* const* d_in, const int* in_sizes, int n_in,
                              void* d_out, int out_size, void* d_ws, size_t ws_size,
                              hipStream_t stream) {
    const int*   tokens = (const int*)  d_in[0];
    const float* Wemb   = (const float*)d_in[1];
    const float* Wq     = (const float*)d_in[2];
    const float* bq     = (const float*)d_in[3];
    const float* Wk     = (const float*)d_in[4];
    const float* bk     = (const float*)d_in[5];
    const float* Wv     = (const float*)d_in[6];
    const float* bv     = (const float*)d_in[7];
    const float* Wo     = (const float*)d_in[8];
    const float* bo     = (const float*)d_in[9];
    const float* ln1g   = (const float*)d_in[10];
    const float* ln1b   = (const float*)d_in[11];
    const float* ln2g   = (const float*)d_in[12];
    const float* ln2b   = (const float*)d_in[13];
    const float* W1     = (const float*)d_in[14];
    const float* b1     = (const float*)d_in[15];
    const float* W2     = (const float*)d_in[16];
    const float* b2     = (const float*)d_in[17];
    const float* Wout   = (const float*)d_in[18];
    const float* bout   = (const float*)d_in[19];
    float* out = (float*)d_out;

    const size_t ND = (size_t)N_ * D_;      // 4,096,000
    const size_t NF = (size_t)N_ * FF_;     // 16,384,000
    const size_t M1 = (size_t)D_ * D_;
    const size_t M4 = (size_t)FF_ * D_;
    const size_t VT = (size_t)64 * 64 * 1024;

    float* x  = (float*)d_ws;
    unsigned short* hb = (unsigned short*)(x + ND);
    unsigned short* qb = hb + ND;
    unsigned short* kb = qb + ND;
    unsigned short* vb = kb + ND;
    unsigned short* ob = vb + ND;
    unsigned short* vt = ob + ND;
    unsigned short* f1 = vt + VT;           // NF bf16 (32.77 MB)
    float* qf = (float*)f1;                 // aliases f1 region (used pre-FFN only)
    float* kf = qf + ND;                    // qf+kf = 32.77 MB, exact fit
    unsigned short* wb = f1 + NF;           // 12M bf16 per-layer weights

    dim3 blk(256);
    embed_kernel<<<N_, blk, 0, stream>>>(tokens, Wemb, x);

    dim3 gD(32, 8);    // D x D
    dim3 gF(32, 32);   // W1: E=4096
    dim3 gCv(12288);
    int rth = N_ * H_ * 32;
    dim3 gR((rth + 255) / 256);
    dim3 gVt(16, 64);
    dim3 gAt(16 * 64);
    dim3 gOut((N_ + 63) / 64, 1);

    for (int l = 0; l < L_; ++l) {
        cvtw_kernel<<<gCv, blk, 0, stream>>>(Wq + l*M1, Wk + l*M1, Wv + l*M1,
                                             Wo + l*M1, W1 + l*M4, W2 + l*M4, wb);
        ln_kernel<<<N_, blk, 0, stream>>>(x, ln1g + l*D_, ln1b + l*D_, hb);
        mgemm_kernel<0,0,0><<<gD, blk, 0, stream>>>(hb, wb,        bq + l*D_,  nullptr, qf, N_, D_,  D_,  0.125f);
        mgemm_kernel<0,0,0><<<gD, blk, 0, stream>>>(hb, wb + M1,   bk + l*D_,  nullptr, kf, N_, D_,  D_,  1.0f);
        mgemm_kernel<0,0,1><<<gD, blk, 0, stream>>>(hb, wb + 2*M1, bv + l*D_,  nullptr, vb, N_, D_,  D_,  1.0f);
        ropecvt_kernel<<<gR, blk, 0, stream>>>(qf, qb);
        ropecvt_kernel<<<gR, blk, 0, stream>>>(kf, kb);
        vtr_kernel<<<gVt, blk, 0, stream>>>(vb, vt);
        mattn_kernel<<<gAt, blk, 0, stream>>>(qb, kb, vt, ob);
        mgemm_kernel<0,1,0><<<gD, blk, 0, stream>>>(ob, wb + 3*M1, bo + l*D_,  x, x,  N_, D_,  D_,  1.0f);
        ln_kernel<<<N_, blk, 0, stream>>>(x, ln2g + l*D_, ln2b + l*D_, hb);
        mgemm_kernel<1,0,1><<<gF, blk, 0, stream>>>(hb, wb + 4*M1, b1 + l*FF_, nullptr, f1, N_, D_,  FF_, 1.0f);
        mgemm_kernel<0,1,0><<<gD, blk, 0, stream>>>(f1, wb + 4*M1 + M4, b2 + l*D_, x, x, N_, FF_, D_,  1.0f);
    }
    gemm_kernel<<<gOut, blk, 0, stream>>>(x, Wout, bout, out, N_, D_, 64);
}